// Round 14
// baseline (164.982 us; speedup 1.0000x reference)
//
#include <hip/hip_runtime.h>
#include <math.h>

constexpr int BATCH = 2, SEQ = 4096, DIM = 512, HEADS = 8, DH = 64, CH = 64;
constexpr int NC = SEQ / CH;        // 64 chunks per (b,h)
constexpr int BH = BATCH * HEADS;   // 16
constexpr int NCHUNK = BH * NC;     // 1024
constexpr int ROWS = BATCH * SEQ;   // 8192
constexpr int DI = HEADS * DH;      // 512
constexpr int TS = 64 * 72;         // bf16 tile: 64 rows, stride 72 elems

typedef __attribute__((ext_vector_type(8))) short short8;
typedef __attribute__((ext_vector_type(4))) short short4v;
typedef __attribute__((ext_vector_type(4))) float f32x4;

// LDS-only barrier: drain lgkm (ds ops) but let global stores stay in flight.
#define LBAR() do { asm volatile("s_waitcnt lgkmcnt(0)" ::: "memory"); \
                    __builtin_amdgcn_s_barrier(); } while (0)

__device__ inline float sigmoidf_(float x){ return 1.f/(1.f+__expf(-x)); }
__device__ inline float dsilu_f(float x){ float s = sigmoidf_(x); return s*(1.f + x*(1.f-s)); }

__device__ inline unsigned short f2b(float f){
  union { float f; unsigned int u; } c; c.f = f;
  unsigned int u = c.u;
  unsigned int r = (u + 0x7FFFu + ((u >> 16) & 1u)) >> 16;
  return (unsigned short)r;
}
__device__ inline float b2f(unsigned short h){
  union { unsigned int u; float f; } c; c.u = ((unsigned int)h) << 16;
  return c.f;
}

// =====================================================================
// 8-wave MFMA 64x64 building blocks (512 threads).
// Wave wid: rows [(wid>>1)*16, +16), cols [(wid&1)*32, +32)
// A-tile: M x K row-major bf16 stride 72; B-tile: N x K row-major stride 72
// =====================================================================
struct MM { int lr, lg, rowbase, colbase; };
__device__ inline MM mmctx(){
  int tid = threadIdx.x;
  int wid = tid >> 6, lane = tid & 63;
  MM m; m.lr = lane & 15; m.lg = lane >> 4;
  m.rowbase = (wid >> 1) * 16; m.colbase = (wid & 1) * 32;
  return m;
}

template<bool SILUA>
__device__ inline void mm64(const unsigned short* A, const unsigned short* B,
                            f32x4 (&acc)[2], const MM& m)
{
  acc[0] = (f32x4){0.f,0.f,0.f,0.f};
  acc[1] = (f32x4){0.f,0.f,0.f,0.f};
  #pragma unroll
  for (int ks = 0; ks < 2; ks++){
    short8 a = *(const short8*)&A[(m.rowbase + m.lr)*72 + ks*32 + m.lg*8];
    if constexpr (SILUA){
      #pragma unroll
      for (int j = 0; j < 8; j++){
        float v = b2f((unsigned short)a[j]);
        v = v * sigmoidf_(v);
        a[j] = (short)f2b(v);
      }
    }
    #pragma unroll
    for (int ct = 0; ct < 2; ct++){
      short8 b = *(const short8*)&B[(m.colbase + ct*16 + m.lr)*72 + ks*32 + m.lg*8];
      acc[ct] = __builtin_amdgcn_mfma_f32_16x16x32_bf16(a, b, acc[ct], 0, 0, 0);
    }
  }
}

__device__ inline void storeN64(unsigned short* R, const f32x4 (&acc)[2], const MM& m, float scale){
  #pragma unroll
  for (int ct = 0; ct < 2; ct++){
    int c  = m.colbase + ct*16 + m.lr;
    int mb = m.rowbase + m.lg*4;
    #pragma unroll
    for (int r = 0; r < 4; r++) R[(mb+r)*72 + c] = f2b(acc[ct][r] * scale);
  }
}
__device__ inline void storeT64(unsigned short* T, const f32x4 (&acc)[2], const MM& m, float scale){
  #pragma unroll
  for (int ct = 0; ct < 2; ct++){
    int c  = m.colbase + ct*16 + m.lr;
    int mb = m.rowbase + m.lg*4;
    short4v p;
    #pragma unroll
    for (int r = 0; r < 4; r++) p[r] = (short)f2b(acc[ct][r] * scale);
    *(short4v*)&T[c*72 + mb] = p;
  }
}
__device__ inline void storeSC(float* S, const f32x4 (&acc)[2], const MM& m, float scale){
  #pragma unroll
  for (int ct = 0; ct < 2; ct++){
    int c  = m.colbase + ct*16 + m.lr;
    int mb = m.rowbase + m.lg*4;
    #pragma unroll
    for (int r = 0; r < 4; r++) S[(mb+r)*66 + c] = acc[ct][r] * scale;
  }
}
// store C^T as bf16 to global (g holds dW^T [out][in]); 8B/lane contiguous
__device__ inline void storeGTb64(unsigned short* __restrict__ G, const f32x4 (&acc)[2],
                                  const MM& m, float scale){
  #pragma unroll
  for (int ct = 0; ct < 2; ct++){
    int c  = m.colbase + ct*16 + m.lr;   // out index
    int mb = m.rowbase + m.lg*4;         // in index base
    short4v p;
    #pragma unroll
    for (int r = 0; r < 4; r++) p[r] = (short)f2b(acc[ct][r] * scale);
    *(short4v*)&G[c*64 + mb] = p;
  }
}

// bf16 global 64x64 -> row LDS; 512 threads (one short8 each)
__device__ inline void loadTileBrow(unsigned short* R, const unsigned short* __restrict__ src,
                                    int stride, int tid){
  int i = tid >> 3, j8 = (tid & 7) * 8;
  *(short8*)&R[i*72 + j8] = *(const short8*)&src[(size_t)i*stride + j8];
}
// bf16 global 64x64 -> row + transposed LDS; 512 threads
__device__ inline void loadTileBrowT(unsigned short* R, unsigned short* T,
                                     const unsigned short* __restrict__ src,
                                     int stride, int tid){
  int i = tid >> 3, j8 = (tid & 7) * 8;
  short8 v = *(const short8*)&src[(size_t)i*stride + j8];
  *(short8*)&R[i*72 + j8] = v;
  #pragma unroll
  for (int jj = 0; jj < 8; jj++) T[(j8+jj)*72 + i] = (unsigned short)v[jj];
}

// =====================================================================
// K-FRONT: blocks [0, ROWS/4)   : wave-per-row rmsnorm (s hi, rq hi with
//                                 pad-zeroing, lr)
//          blocks [ROWS/4, +260): weight prep (transpose/convert bf16)
// =====================================================================
__global__ __launch_bounds__(256) void k_front(
    const float* __restrict__ seq, const float* __restrict__ wsn,
    const float* __restrict__ wrn, const float* __restrict__ wstep,
    const float* __restrict__ w_kv, const float* __restrict__ w_q,
    const float* __restrict__ wcomb,
    const float* __restrict__ wq, const float* __restrict__ wk,
    const float* __restrict__ wv1, const float* __restrict__ wv2,
    unsigned short* __restrict__ s_hi,
    unsigned short* __restrict__ rq_hi, float* __restrict__ lrp,
    unsigned short* __restrict__ wkvT_hi,
    unsigned short* __restrict__ wqT_hi, unsigned short* __restrict__ wcombT_hi,
    unsigned short* __restrict__ wpre)
{
  __shared__ float t[64][65];
  int tid = threadIdx.x;
  if (blockIdx.x >= ROWS/4){
    int blk = blockIdx.x - ROWS/4;
    if (blk < 256){
      const float* src; unsigned short *dhi;
      int R, C, bx, by;
      if (blk < 128){ src = w_kv;  dhi = wkvT_hi;  R = DIM; C = 2*DI; bx = blk & 15; by = blk >> 4; }
      else if (blk < 192){ int q = blk - 128; src = w_q;   dhi = wqT_hi;    R = DIM; C = DI;  bx = q & 7; by = q >> 3; }
      else               { int q = blk - 192; src = wcomb; dhi = wcombT_hi; R = DI;  C = DIM; bx = q & 7; by = q >> 3; }
      int c0 = bx * 64, r0 = by * 64;
      #pragma unroll
      for (int it = 0; it < 16; it++){
        int idx = it*256 + tid;
        int i = idx >> 6, j = idx & 63;
        t[i][j] = src[(size_t)(r0+i)*C + c0 + j];
      }
      __syncthreads();
      #pragma unroll
      for (int it = 0; it < 16; it++){
        int idx = it*256 + tid;
        int i = idx >> 6, j = idx & 63;
        dhi[(size_t)(c0+i)*R + r0 + j] = f2b(t[j][i]);
      }
    } else {
      int b = blk - 256;
      const float* src = (b==0) ? wq : (b==1) ? wk : (b==2) ? wv1 : wv2;
      #pragma unroll
      for (int it = 0; it < 16; it++){
        int idx = it*256 + tid;
        int i = idx >> 6, j = idx & 63;
        t[i][j] = src[i*64 + j];
      }
      __syncthreads();
      #pragma unroll
      for (int it = 0; it < 16; it++){
        int idx = it*256 + tid;
        int i = idx >> 6, j = idx & 63;
        wpre[b*4096 + i*64 + j] = f2b(t[j][i]);
        if (b == 3) wpre[4*4096 + i*64 + j] = f2b(t[i][j]);
      }
    }
    return;
  }
  // ---- rmsnorm part ----
  int wid = tid >> 6, lane = tid & 63;
  int row = blockIdx.x * 4 + wid;
  int b = row >> 12, tt = row & 4095;
  const float* x = seq + (size_t)row * DIM;
  float4 v0 = *(const float4*)&x[lane*4];
  float4 v1 = *(const float4*)&x[256 + lane*4];
  float xv[8] = {v0.x, v0.y, v0.z, v0.w, v1.x, v1.y, v1.z, v1.w};
  float ss = 0.f;
  #pragma unroll
  for (int j = 0; j < 8; j++) ss += xv[j]*xv[j];
  #pragma unroll
  for (int m = 1; m < 64; m <<= 1) ss += __shfl_xor(ss, m);
  float rinv = rsqrtf(ss * (1.f/DIM) + 1e-6f);

  float4 w0 = *(const float4*)&wsn[lane*4];
  float4 w1 = *(const float4*)&wsn[256 + lane*4];
  float wv[8] = {w0.x, w0.y, w0.z, w0.w, w1.x, w1.y, w1.z, w1.w};
  float sv[8];
  short4v h0, h1;
  #pragma unroll
  for (int j = 0; j < 8; j++){
    sv[j] = xv[j] * rinv * wv[j];
    unsigned short hi = f2b(sv[j]);
    if (j < 4) h0[j] = (short)hi; else h1[j-4] = (short)hi;
  }
  size_t sbase = (size_t)row*DIM + lane*4;
  *(short4v*)&s_hi[sbase] = h0; *(short4v*)&s_hi[sbase + 256] = h1;

  if (tt >= CH){
    float4 r0 = *(const float4*)&wrn[lane*4];
    float4 r1 = *(const float4*)&wrn[256 + lane*4];
    float rv[8] = {r0.x, r0.y, r0.z, r0.w, r1.x, r1.y, r1.z, r1.w};
    short4v rh0, rh1;
    #pragma unroll
    for (int j = 0; j < 8; j++){
      float q = xv[j] * rinv * rv[j];
      unsigned short hi = f2b(q);
      if (j < 4) rh0[j] = (short)hi; else rh1[j-4] = (short)hi;
    }
    size_t rbase = ((size_t)b*SEQ + (tt - CH))*DIM + lane*4;
    *(short4v*)&rq_hi[rbase] = rh0; *(short4v*)&rq_hi[rbase + 256] = rh1;
  } else {
    short4v z; z[0]=0; z[1]=0; z[2]=0; z[3]=0;
    size_t rbase = ((size_t)b*SEQ + (SEQ - CH + tt))*DIM + lane*4;
    *(short4v*)&rq_hi[rbase] = z; *(short4v*)&rq_hi[rbase + 256] = z;
  }

  float acc[8] = {0.f,0.f,0.f,0.f,0.f,0.f,0.f,0.f};
  #pragma unroll
  for (int j = 0; j < 8; j++){
    int e = (j < 4) ? (lane*4 + j) : (256 + lane*4 + (j-4));
    float4 wa = *(const float4*)&wstep[e*8];
    float4 wb = *(const float4*)&wstep[e*8 + 4];
    acc[0] += sv[j]*wa.x; acc[1] += sv[j]*wa.y; acc[2] += sv[j]*wa.z; acc[3] += sv[j]*wa.w;
    acc[4] += sv[j]*wb.x; acc[5] += sv[j]*wb.y; acc[6] += sv[j]*wb.z; acc[7] += sv[j]*wb.w;
  }
  #pragma unroll
  for (int m = 1; m < 64; m <<= 1){
    #pragma unroll
    for (int h = 0; h < 8; h++) acc[h] += __shfl_xor(acc[h], m);
  }
  float a = acc[0];
  #pragma unroll
  for (int h = 1; h < 8; h++) a = (lane == h) ? acc[h] : a;
  if (lane < 8)
    lrp[(size_t)row*HEADS + lane] = __expf(-15.f * sigmoidf_(a));
}

// =====================================================================
// K-MID (1-D, 896 blocks, 36.8KB LDS -> 4 blk/CU):
//  [0,512)  : kv GEMM  s_hi[8192][512] @ wkvT_hi[1024][512]^T -> kvb bf16
//  [512,768): q  GEMM  rq_hi @ wqT_hi -> qb bf16
//  [768,896): chunk stats
// =====================================================================
__global__ __launch_bounds__(256, 4) void k_mid(
    const unsigned short* __restrict__ s_hi, const unsigned short* __restrict__ rq_hi,
    const unsigned short* __restrict__ wkvT_hi, const unsigned short* __restrict__ wqT_hi,
    unsigned short* __restrict__ kvb, unsigned short* __restrict__ qb,
    const float* __restrict__ lrp, const float* __restrict__ wmom,
    const float* __restrict__ wdec,
    float* __restrict__ mg, float* __restrict__ dec, float* __restrict__ lrc)
{
  __shared__ __align__(16) unsigned short AhS[128*72];
  __shared__ __align__(16) unsigned short BhS[128*72];
  int tid = threadIdx.x;
  int blk = blockIdx.x;
  if (blk >= 768){
    int bid = blk - 768;
    float* smean = (float*)AhS;   // 2KB overlay
    int b = bid >> 6, ch = bid & 63;
    size_t off = ((size_t)(b*SEQ + ch*CH)) * DIM;
    for (int e = tid; e < DIM; e += 256){
      float acc = 0.f;
      for (int i = 0; i < CH; i++)
        acc += b2f(s_hi[off + (size_t)i*DIM + e]);
      smean[e] = acc * (1.f/CH);
    }
    __syncthreads();
    int gh = tid >> 5, l = tid & 31;
    float am = 0.f, ad = 0.f;
    for (int e = l; e < DIM; e += 32){
      float v = smean[e];
      am += v * wmom[e*HEADS + gh];
      ad += v * wdec[e*HEADS + gh];
    }
    const float* lrbase = lrp + ((size_t)(b*SEQ + ch*CH)) * HEADS + gh;
    float al = lrbase[(size_t)l*HEADS] + lrbase[(size_t)(l+32)*HEADS];
    #pragma unroll
    for (int m = 1; m < 32; m <<= 1){
      am += __shfl_xor(am, m);
      ad += __shfl_xor(ad, m);
      al += __shfl_xor(al, m);
    }
    if (l == 0){
      int o = (b*HEADS + gh)*NC + ch;
      mg[o]  = sigmoidf_(am);
      dec[o] = sigmoidf_(ad);
      lrc[o] = al * (1.f/CH);
    }
    return;
  }
  const unsigned short *Ahg, *Bhg; unsigned short* Cb;
  int N, nwg, bid;
  if (blk < 512){ Ahg = s_hi;  Bhg = wkvT_hi; Cb = kvb; N = 2*DI; nwg = 512; bid = blk; }
  else          { Ahg = rq_hi; Bhg = wqT_hi;  Cb = qb;  N = DI;   nwg = 256; bid = blk - 512; }
  const int K = DIM;
  int ntil = N >> 7;
  int swz = (bid & 7) * (nwg >> 3) + (bid >> 3);
  int m0 = (swz / ntil) * 128;
  int n0 = (swz % ntil) * 128;
  int wid = tid >> 6, lane = tid & 63;
  int lr = lane & 15, lg = lane >> 4;
  int wr = (wid >> 1) * 64, wc = (wid & 1) * 64;
  f32x4 acc[4][4];
  #pragma unroll
  for (int r = 0; r < 4; r++)
    #pragma unroll
    for (int c = 0; c < 4; c++) acc[r][c] = (f32x4){0.f,0.f,0.f,0.f};

  for (int k0 = 0; k0 < K; k0 += 64){
    #pragma unroll
    for (int it = 0; it < 4; it++){
      int idx = it*256 + tid;
      int row = idx >> 3, col8 = (idx & 7) * 8;
      *(short8*)&AhS[row*72 + col8] = *(const short8*)&Ahg[(size_t)(m0+row)*K + k0 + col8];
      *(short8*)&BhS[row*72 + col8] = *(const short8*)&Bhg[(size_t)(n0+row)*K + k0 + col8];
    }
    __syncthreads();
    #pragma unroll
    for (int ks = 0; ks < 2; ks++){
      short8 ah[4], bh[4];
      #pragma unroll
      for (int i = 0; i < 4; i++){
        ah[i] = *(const short8*)&AhS[(wr + i*16 + lr)*72 + ks*32 + lg*8];
        bh[i] = *(const short8*)&BhS[(wc + i*16 + lr)*72 + ks*32 + lg*8];
      }
      #pragma unroll
      for (int r = 0; r < 4; r++)
        #pragma unroll
        for (int c = 0; c < 4; c++)
          acc[r][c] = __builtin_amdgcn_mfma_f32_16x16x32_bf16(ah[r], bh[c], acc[r][c], 0, 0, 0);
    }
    __syncthreads();
  }
  #pragma unroll
  for (int rt = 0; rt < 4; rt++)
    #pragma unroll
    for (int ct = 0; ct < 4; ct++){
      int col = n0 + wc + ct*16 + lr;
      int rowb = m0 + wr + rt*16 + lg*4;
      #pragma unroll
      for (int r = 0; r < 4; r++)
        Cb[(size_t)(rowb+r)*N + col] = f2b(acc[rt][ct][r]);
    }
}

// =====================================================================
// K-GEMM (combine): C = A @ B^T 1-pass bf16 -> bf16, XCD-swizzled
// =====================================================================
__global__ __launch_bounds__(256, 4) void k_gemm1(
    const unsigned short* __restrict__ Ahg, const unsigned short* __restrict__ Bhg,
    unsigned short* __restrict__ Cb, int M, int N, int K)
{
  __shared__ __align__(16) unsigned short AhS[128*72];
  __shared__ __align__(16) unsigned short BhS[128*72];
  int tid = threadIdx.x;
  int nwg = gridDim.x * gridDim.y;
  int bid = blockIdx.y * gridDim.x + blockIdx.x;
  int swz = (bid & 7) * (nwg >> 3) + (bid >> 3);
  int m0 = (swz / gridDim.x) * 128;
  int n0 = (swz % gridDim.x) * 128;
  int wid = tid >> 6, lane = tid & 63;
  int lr = lane & 15, lg = lane >> 4;
  int wr = (wid >> 1) * 64, wc = (wid & 1) * 64;
  f32x4 acc[4][4];
  #pragma unroll
  for (int r = 0; r < 4; r++)
    #pragma unroll
    for (int c = 0; c < 4; c++) acc[r][c] = (f32x4){0.f,0.f,0.f,0.f};

  for (int k0 = 0; k0 < K; k0 += 64){
    #pragma unroll
    for (int it = 0; it < 4; it++){
      int idx = it*256 + tid;
      int row = idx >> 3, col8 = (idx & 7) * 8;
      *(short8*)&AhS[row*72 + col8] = *(const short8*)&Ahg[(size_t)(m0+row)*K + k0 + col8];
      *(short8*)&BhS[row*72 + col8] = *(const short8*)&Bhg[(size_t)(n0+row)*K + k0 + col8];
    }
    __syncthreads();
    #pragma unroll
    for (int ks = 0; ks < 2; ks++){
      short8 ah[4], bh[4];
      #pragma unroll
      for (int i = 0; i < 4; i++){
        ah[i] = *(const short8*)&AhS[(wr + i*16 + lr)*72 + ks*32 + lg*8];
        bh[i] = *(const short8*)&BhS[(wc + i*16 + lr)*72 + ks*32 + lg*8];
      }
      #pragma unroll
      for (int r = 0; r < 4; r++)
        #pragma unroll
        for (int c = 0; c < 4; c++)
          acc[r][c] = __builtin_amdgcn_mfma_f32_16x16x32_bf16(ah[r], bh[c], acc[r][c], 0, 0, 0);
    }
    __syncthreads();
  }
  #pragma unroll
  for (int rt = 0; rt < 4; rt++)
    #pragma unroll
    for (int ct = 0; ct < 4; ct++){
      int col = n0 + wc + ct*16 + lr;
      int rowb = m0 + wr + rt*16 + lg*4;
      #pragma unroll
      for (int r = 0; r < 4; r++)
        Cb[(size_t)(rowb+r)*N + col] = f2b(acc[rt][ct][r]);
    }
}

// =====================================================================
// K4: per-chunk attention fwd+bwd (8 waves, 512 thr, 127.5KB LDS)
// kvb [ROWS][2*DI] bf16: keys half = X, values half = target (bf16)
// Barriers are lgkm-only: dW global stores drain in background.
// =====================================================================
__global__ __launch_bounds__(512) void k_grads(
    const unsigned short* __restrict__ kvb,
    const unsigned short* __restrict__ wpre,
    const float* __restrict__ lrc, unsigned short* __restrict__ g)
{
  __shared__ __align__(16) unsigned short sm[12*TS];
  __shared__ __align__(16) float SC[64*66];
  unsigned short *Xr = sm,        *XT = sm + TS,
                 *s2 = sm + 2*TS, *s3 = sm + 3*TS, *s4 = sm + 4*TS,
                 *s5 = sm + 5*TS, *s6 = sm + 6*TS, *s7 = sm + 7*TS,
                 *s8 = sm + 8*TS, *s9 = sm + 9*TS, *s10 = sm + 10*TS,
                 *s11 = sm + 11*TS;
  unsigned short *SCu = (unsigned short*)SC;
  int chunk = blockIdx.x;
  int bh = chunk >> 6, t = chunk & 63;
  int b = bh >> 3, h = bh & 7;
  int tid = threadIdx.x;
  MM M = mmctx();
  const unsigned short* xb = kvb + ((size_t)(b*SEQ + t*CH)) * (2*DI) + h*DH;
  const unsigned short* tb = xb + DI;   // bf16 target
  float negLr = -lrc[bh*NC + t];
  f32x4 acc[2], accV[2];

  loadTileBrowT(Xr, XT, xb, 2*DI, tid);
  loadTileBrow(s2, wpre + 0*4096, 64, tid);   // WqT  [out][in]
  loadTileBrow(s3, wpre + 1*4096, 64, tid);   // WkT
  loadTileBrow(s4, wpre + 2*4096, 64, tid);   // Wv1T
  loadTileBrow(s5, wpre + 3*4096, 64, tid);   // Wv2T
  loadTileBrow(s6, wpre + 4*4096, 64, tid);   // Wv2 row [in][out]
  LBAR();
  mm64<false>(Xr, s2, acc, M);
  storeN64(s7, acc, M, 1.f); storeT64(s8, acc, M, 1.f);
  mm64<false>(Xr, s3, acc, M);
  storeN64(s9, acc, M, 1.f); storeT64(s10, acc, M, 1.f);
  mm64<false>(Xr, s4, accV, M);
  storeN64(s11, accV, M, 1.f);
  LBAR();
  storeT64(s2, accV, M, 1.f);
  mm64<false>(s7, s9, acc, M);
  storeSC(SC, acc, M, 0.125f);
  LBAR();
  {
    int row = tid >> 3, q = tid & 7;
    float p[8];
    float mx = -1e30f;
    #pragma unroll
    for (int cc = 0; cc < 8; cc++){
      int col = q*8 + cc;
      float x = SC[row*66 + col];
      p[cc] = (col <= row) ? x : -1e9f;
      mx = fmaxf(mx, p[cc]);
    }
    mx = fmaxf(mx, __shfl_xor(mx, 1));
    mx = fmaxf(mx, __shfl_xor(mx, 2));
    mx = fmaxf(mx, __shfl_xor(mx, 4));
    float sum = 0.f;
    #pragma unroll
    for (int cc = 0; cc < 8; cc++){ p[cc] = __expf(p[cc] - mx); sum += p[cc]; }
    sum += __shfl_xor(sum, 1);
    sum += __shfl_xor(sum, 2);
    sum += __shfl_xor(sum, 4);
    float inv = 1.f / sum;
    #pragma unroll
    for (int cc = 0; cc < 8; cc++){
      int col = q*8 + cc;
      unsigned short hh = f2b(p[cc] * inv);
      s7[row*72 + col] = hh;
      s9[col*72 + row] = hh;
    }
  }
  LBAR();
  mm64<false>(s7, s2, acc, M);
  storeN64(s3, acc, M, 1.f); storeT64(s4, acc, M, 1.f);
  LBAR();
  mm64<true>(s3, s5, acc, M);
  #pragma unroll
  for (int ct = 0; ct < 2; ct++){
    int c  = M.colbase + ct*16 + M.lr;
    int mb = M.rowbase + M.lg*4;
    #pragma unroll
    for (int r = 0; r < 4; r++){
      float t2 = (acc[ct][r] - b2f(tb[(size_t)(mb+r)*(2*DI) + c])) * (2.f/64.f);
      unsigned short hh = f2b(t2);
      Xr[(mb+r)*72 + c] = hh;
      s2[c*72 + (mb+r)] = hh;
    }
  }
  LBAR();
  mm64<true>(s4, s2, acc, M);
  storeGTb64(g + ((size_t)(3*NCHUNK + chunk))*4096, acc, M, negLr);
  mm64<false>(Xr, s6, acc, M);
  #pragma unroll
  for (int ct = 0; ct < 2; ct++){
    int c  = M.colbase + ct*16 + M.lr;
    int mb = M.rowbase + M.lg*4;
    #pragma unroll
    for (int r = 0; r < 4; r++){
      float x = b2f(s3[(mb+r)*72 + c]);
      float d = acc[ct][r] * dsilu_f(x);
      unsigned short hh = f2b(d);
      s5[(mb+r)*72 + c] = hh;
      SCu[c*72 + (mb+r)] = hh;
    }
  }
  LBAR();
  mm64<false>(s5, s11, acc, M);
  storeN64(Xr, acc, M, 1.f);
  mm64<false>(s9, SCu, acc, M);
  storeT64(s2, acc, M, 1.f);
  LBAR();
  {
    int row = tid >> 3, q = tid & 7;
    float da[8], a[8], rs = 0.f;
    #pragma unroll
    for (int cc = 0; cc < 8; cc++){
      int col = q*8 + cc;
      da[cc] = b2f(Xr[row*72 + col]);
      a[cc]  = b2f(s7[row*72 + col]);
      rs += da[cc]*a[cc];
    }
    rs += __shfl_xor(rs, 1);
    rs += __shfl_xor(rs, 2);
    rs += __shfl_xor(rs, 4);
    #pragma unroll
    for (int cc = 0; cc < 8; cc++){
      int col = q*8 + cc;
      unsigned short hh = f2b(a[cc] * (da[cc] - rs));
      s3[row*72 + col] = hh;
      s6[col*72 + row] = hh;
    }
  }
  mm64<false>(XT, s2, acc, M);
  storeGTb64(g + ((size_t)(2*NCHUNK + chunk))*4096, acc, M, negLr);
  LBAR();
  mm64<false>(s3, s10, acc, M);
  storeT64(Xr, acc, M, 0.125f);
  mm64<false>(s6, s8, acc, M);
  storeT64(s2, acc, M, 0.125f);
  LBAR();
  mm64<false>(XT, Xr, acc, M);
  storeGTb64(g + ((size_t)(0*NCHUNK + chunk))*4096, acc, M, negLr);
  mm64<false>(XT, s2, acc, M);
  storeGTb64(g + ((size_t)(1*NCHUNK + chunk))*4096, acc, M, negLr);
}

// =====================================================================
// K5: double associative scan over chunks; bf16 in/out; dist-2 prefetch
// =====================================================================
__global__ __launch_bounds__(256) void k_scan(
    unsigned short* __restrict__ g, const float* __restrict__ mg, const float* __restrict__ dec,
    const float* __restrict__ wq, const float* __restrict__ wk,
    const float* __restrict__ wv1, const float* __restrict__ wv2)
{
  int idx = blockIdx.x * 256 + threadIdx.x;   // 0..131071
  int e = (idx & 2047) * 2;                   // even element index (out*64+in)
  int bh = (idx >> 11) & 15;
  int name = idx >> 15;
  const float* past = (name == 0) ? wq : (name == 1) ? wk : (name == 2) ? wv1 : wv2;
  float base0 = past[(e & 63)*64 + (e >> 6)];
  float base1 = past[((e+1) & 63)*64 + ((e+1) >> 6)];
  const float* mgb = mg + bh*NC;
  const float* dcb = dec + bh*NC;
  size_t off = ((size_t)name*NCHUNK + (size_t)bh*NC)*4096 + e;
  float m0 = 0.f, u0 = 0.f, m1 = 0.f, u1 = 0.f;
  unsigned int v0 = *(const unsigned int*)&g[off];
  unsigned int v1 = *(const unsigned int*)&g[off + 4096];
  for (int t = 0; t < NC; t++){
    unsigned int vn = 0;
    if (t + 2 < NC) vn = *(const unsigned int*)&g[off + 2*4096];
    float su0 = b2f((unsigned short)(v0 & 0xffff));
    float su1 = b2f((unsigned short)(v0 >> 16));
    float gm = mgb[t], dc = dcb[t];
    m0 = gm*m0 + su0;  u0 = (1.f - dc)*u0 + m0;
    m1 = gm*m1 + su1;  u1 = (1.f - dc)*u1 + m1;
    unsigned int w = (unsigned int)f2b(base0 + u0) | ((unsigned int)f2b(base1 + u1) << 16);
    *(unsigned int*)&g[off] = w;
    v0 = v1; v1 = vn; off += 4096;
  }
}

// =====================================================================
// K6: retrieval attention; 8 waves, 72KB LDS, 6-barrier schedule
// slots: Xr=X | Wt: W0 -> V^T | Qr: Q | Kr: K -> H | Vt: W2 | Hr: W1 -> W3
// =====================================================================
__global__ __launch_bounds__(512, 4) void k_retrieve(
    const unsigned short* __restrict__ qb, const unsigned short* __restrict__ Wg,
    unsigned short* __restrict__ vals_hi)
{
  __shared__ __align__(16) unsigned short sm[6*TS];
  __shared__ __align__(16) float SC[64*66];
  unsigned short *Xr = sm,       *Wt = sm + TS,   *Qr = sm + 2*TS,
                 *Kr = sm + 3*TS, *Vt = sm + 4*TS, *Hr = sm + 5*TS;
  unsigned short *Ar = (unsigned short*)SC;
  int chunk = blockIdx.x;
  int bh = chunk >> 6, t = chunk & 63;
  int b = bh >> 3, h = bh & 7;
  int tid = threadIdx.x;
  MM M = mmctx();
  const unsigned short* xb = qb + ((size_t)(b*SEQ + t*CH)) * DI + h*DH;
  f32x4 acc[2], acc2[2];

  // P0: X, W0 (wq), W1 (wk)
  loadTileBrow(Xr, xb, DI, tid);
  loadTileBrow(Wt, Wg + ((size_t)(0*NCHUNK + chunk))*4096, 64, tid);
  loadTileBrow(Hr, Wg + ((size_t)(1*NCHUNK + chunk))*4096, 64, tid);
  LBAR();
  // P1: Q and K; park W2 in Vt
  mm64<false>(Xr, Wt, acc, M);  storeN64(Qr, acc, M, 1.f);
  mm64<false>(Xr, Hr, acc2, M); storeN64(Kr, acc2, M, 1.f);
  loadTileBrow(Vt, Wg + ((size_t)(2*NCHUNK + chunk))*4096, 64, tid);
  LBAR();
  // P2: V^T -> Wt (W0 dead); S = Q K^T /8 -> SC; W3 -> Hr (W1 dead)
  mm64<false>(Xr, Vt, acc, M);  storeT64(Wt, acc, M, 1.f);
  mm64<false>(Qr, Kr, acc2, M); storeSC(SC, acc2, M, 0.125f);
  loadTileBrow(Hr, Wg + ((size_t)(3*NCHUNK + chunk))*4096, 64, tid);
  LBAR();
  // P3: causal softmax SC -> Ar (overlay)
  {
    int row = tid >> 3, q = tid & 7;
    float p[8];
    float mx = -1e30f;
    #pragma unroll
    for (int cc = 0; cc < 8; cc++){
      int col = q*8 + cc;
      float x = SC[row*66 + col];
      p[cc] = (col <= row) ? x : -1e9f;
      mx = fmaxf(mx, p[cc]);
    }
    mx = fmaxf(mx, __shfl_xor(mx, 1));
    mx = fmaxf(mx, __shfl_xor(mx, 2));
    mx = fmaxf(mx, __shfl_xor(mx, 4));
    float sum = 0.f;
    #pragma unroll
    for (int cc = 0; cc < 8; cc++){ p[cc] = __expf(p[cc] - mx); sum += p[cc]; }
    sum += __shfl_xor(sum, 1);
    sum += __shfl_xor(sum, 2);
    sum += __shfl_xor(sum, 4);
    float inv = 1.f / sum;
    LBAR();   // all SC reads complete before overlay write
    #pragma unroll
    for (int cc = 0; cc < 8; cc++){
      int col = q*8 + cc;
      Ar[row*72 + col] = f2b(p[cc] * inv);
    }
  }
  LBAR();
  // P4: H = A @ V^T(Wt) -> Kr (K dead)
  mm64<false>(Ar, Wt, acc, M); storeN64(Kr, acc, M, 1.f);
  LBAR();
  // P5: out = silu(H) @ W3
  mm64<true>(Kr, Hr, acc, M);
  #pragma unroll
  for (int ct = 0; ct < 2; ct++){
    int c  = M.colbase + ct*16 + M.lr;
    int mb = M.rowbase + M.lg*4;
    #pragma unroll
    for (int r = 0; r < 4; r++){
      size_t o = ((size_t)(b*SEQ + t*CH + mb + r))*DI + h*DH + c;
      vals_hi[o] = f2b(acc[ct][r]);
    }
  }
}

// =====================================================================
// K8: final rmsnorm + shift (wave-per-row, bf16 input); zeros rows r<CH
// =====================================================================
__global__ __launch_bounds__(256) void k_outnorm(
    const unsigned short* __restrict__ tmp, const float* __restrict__ wpn,
    float* __restrict__ out)
{
  int wid = threadIdx.x >> 6, lane = threadIdx.x & 63;
  int row = blockIdx.x * 4 + wid;           // 0..8191
  int b = row >> 12, r = row & 4095;
  float* dst = out + ((size_t)b*SEQ + r) * DIM;
  if (r < CH){
    float4 z = make_float4(0.f, 0.f, 0.f, 0.f);
    *(float4*)&dst[lane*8] = z;
    *(float4*)&dst[lane*8 + 4] = z;
    return;
  }
  const unsigned short* src = tmp + ((size_t)b*SEQ + (r - CH)) * DIM;
  short8 t0 = *(const short8*)&src[lane*8];
  float xv[8];
  #pragma unroll
  for (int j = 0; j < 8; j++) xv[j] = b2f((unsigned short)t0[j]);
  float ss = 0.f;
  #pragma unroll
  for (int j = 0; j < 8; j++) ss += xv[j]*xv[j];
  #pragma unroll
  for (int m = 1; m < 64; m <<= 1) ss += __shfl_xor(ss, m);
  float rinv = rsqrtf(ss * (1.f/DIM) + 1e-6f);
  float4 o0, o1;
  o0.x = xv[0]*rinv*wpn[lane*8+0]; o0.y = xv[1]*rinv*wpn[lane*8+1];
  o0.z = xv[2]*rinv*wpn[lane*8+2]; o0.w = xv[3]*rinv*wpn[lane*8+3];
  o1.x = xv[4]*rinv*wpn[lane*8+4]; o1.y = xv[5]*rinv*wpn[lane*8+5];
  o1.z = xv[6]*rinv*wpn[lane*8+6]; o1.w = xv[7]*rinv*wpn[lane*8+7];
  *(float4*)&dst[lane*8] = o0;
  *(float4*)&dst[lane*8 + 4] = o1;
}

// =====================================================================
extern "C" void kernel_launch(void* const* d_in, const int* in_sizes, int n_in,
                              void* d_out, int out_size, void* d_ws, size_t ws_size,
                              hipStream_t stream)
{
  (void)in_sizes; (void)n_in; (void)ws_size; (void)out_size;
  const float* seq   = (const float*)d_in[0];
  const float* wsn   = (const float*)d_in[1];
  const float* wrn   = (const float*)d_in[2];
  const float* wpn   = (const float*)d_in[3];
  const float* w_q   = (const float*)d_in[4];
  const float* w_kv  = (const float*)d_in[5];
  const float* wstep = (const float*)d_in[6];
  const float* wmom  = (const float*)d_in[7];
  const float* wdec  = (const float*)d_in[8];
  const float* wcomb = (const float*)d_in[9];
  const float* wq    = (const float*)d_in[10];
  const float* wk    = (const float*)d_in[11];
  const float* wv1   = (const float*)d_in[12];
  const float* wv2   = (const float*)d_in[13];
  float* out = (float*)d_out;

  char* p = (char*)d_ws;
  unsigned short* s_hi  = (unsigned short*)p; p += (size_t)ROWS*DIM*2;
  unsigned short* rq_hi = (unsigned short*)p; p += (size_t)ROWS*DIM*2;
  unsigned short* kvb   = (unsigned short*)p; p += (size_t)ROWS*2*DI*2;  // keys+target bf16
  unsigned short* qb    = (unsigned short*)p; p += (size_t)ROWS*DI*2;
  unsigned short* g     = (unsigned short*)p; p += (size_t)4*NCHUNK*4096*2;  // 32 MB
  float* lrp            = (float*)p;          p += (size_t)ROWS*HEADS*4;
  float* mg             = (float*)p;          p += (size_t)BH*NC*4;
  float* dec            = (float*)p;          p += (size_t)BH*NC*4;
  float* lrc            = (float*)p;          p += (size_t)BH*NC*4;
  unsigned short* wkvT_hi   = (unsigned short*)p; p += (size_t)(2*DI)*DIM*2;
  unsigned short* wqT_hi    = (unsigned short*)p; p += (size_t)DI*DIM*2;
  unsigned short* wcombT_hi = (unsigned short*)p; p += (size_t)DIM*DI*2;
  unsigned short* wpre      = (unsigned short*)p; p += (size_t)5*4096*2;
  unsigned short* vals_hi   = (unsigned short*)p; p += (size_t)ROWS*DI*2;
  // aliases over dead regions:
  unsigned short* tmp = s_hi;              // s_hi dead after k_mid

  // 1) rmsnorm + all weight prep (independent roots, one launch)
  k_front<<<ROWS/4 + 260, 256, 0, stream>>>(
      seq, wsn, wrn, wstep, w_kv, w_q, wcomb, wq, wk, wv1, wv2,
      s_hi, rq_hi, lrp, wkvT_hi, wqT_hi, wcombT_hi, wpre);
  // 2) kv GEMM (N=1024) + q GEMM + chunk stats, one 1-D launch, 4 blk/CU
  k_mid<<<896, 256, 0, stream>>>(
      s_hi, rq_hi, wkvT_hi, wqT_hi, kvb, qb,
      lrp, wmom, wdec, mg, dec, lrc);
  // 3) per-chunk grads
  k_grads<<<NCHUNK, 512, 0, stream>>>(kvb, wpre, lrc, g);
  // 4) scan
  k_scan<<<(4*BH*2048)/256, 256, 0, stream>>>(g, mg, dec, wq, wk, wv1, wv2);
  // 5) retrieval
  k_retrieve<<<NCHUNK, 512, 0, stream>>>(qb, g, vals_hi);
  // 6) combine GEMM (bf16 -> bf16 tmp)
  k_gemm1<<<dim3(DIM/128, ROWS/128), 256, 0, stream>>>(
      vals_hi, wcombT_hi, tmp, ROWS, DIM, DI);
  // 7) final norm + shift (includes zeroing of first CH rows)
  k_outnorm<<<ROWS/4, 256, 0, stream>>>(tmp, wpn, out);
}

// Round 15
// 152.135 us; speedup vs baseline: 1.0844x; 1.0844x over previous
//
#include <hip/hip_runtime.h>
#include <math.h>

constexpr int BATCH = 2, SEQ = 4096, DIM = 512, HEADS = 8, DH = 64, CH = 64;
constexpr int NC = SEQ / CH;        // 64 chunks per (b,h)
constexpr int BH = BATCH * HEADS;   // 16
constexpr int NCHUNK = BH * NC;     // 1024
constexpr int ROWS = BATCH * SEQ;   // 8192
constexpr int DI = HEADS * DH;      // 512
constexpr int TS = 64 * 72;         // bf16 tile: 64 rows, stride 72 elems

typedef __attribute__((ext_vector_type(8))) short short8;
typedef __attribute__((ext_vector_type(4))) short short4v;
typedef __attribute__((ext_vector_type(4))) float f32x4;

__device__ inline float sigmoidf_(float x){ return 1.f/(1.f+__expf(-x)); }
__device__ inline float dsilu_f(float x){ float s = sigmoidf_(x); return s*(1.f + x*(1.f-s)); }

__device__ inline unsigned short f2b(float f){
  union { float f; unsigned int u; } c; c.f = f;
  unsigned int u = c.u;
  unsigned int r = (u + 0x7FFFu + ((u >> 16) & 1u)) >> 16;
  return (unsigned short)r;
}
__device__ inline float b2f(unsigned short h){
  union { unsigned int u; float f; } c; c.u = ((unsigned int)h) << 16;
  return c.f;
}

// =====================================================================
// 8-wave MFMA 64x64 building blocks (512 threads).
// Wave wid: rows [(wid>>1)*16, +16), cols [(wid&1)*32, +32)
// A-tile: M x K row-major bf16 stride 72; B-tile: N x K row-major stride 72
// =====================================================================
struct MM { int lr, lg, rowbase, colbase; };
__device__ inline MM mmctx(){
  int tid = threadIdx.x;
  int wid = tid >> 6, lane = tid & 63;
  MM m; m.lr = lane & 15; m.lg = lane >> 4;
  m.rowbase = (wid >> 1) * 16; m.colbase = (wid & 1) * 32;
  return m;
}

template<bool SILUA>
__device__ inline void mm64(const unsigned short* A, const unsigned short* B,
                            f32x4 (&acc)[2], const MM& m)
{
  acc[0] = (f32x4){0.f,0.f,0.f,0.f};
  acc[1] = (f32x4){0.f,0.f,0.f,0.f};
  #pragma unroll
  for (int ks = 0; ks < 2; ks++){
    short8 a = *(const short8*)&A[(m.rowbase + m.lr)*72 + ks*32 + m.lg*8];
    if constexpr (SILUA){
      #pragma unroll
      for (int j = 0; j < 8; j++){
        float v = b2f((unsigned short)a[j]);
        v = v * sigmoidf_(v);
        a[j] = (short)f2b(v);
      }
    }
    #pragma unroll
    for (int ct = 0; ct < 2; ct++){
      short8 b = *(const short8*)&B[(m.colbase + ct*16 + m.lr)*72 + ks*32 + m.lg*8];
      acc[ct] = __builtin_amdgcn_mfma_f32_16x16x32_bf16(a, b, acc[ct], 0, 0, 0);
    }
  }
}

__device__ inline void storeN64(unsigned short* R, const f32x4 (&acc)[2], const MM& m, float scale){
  #pragma unroll
  for (int ct = 0; ct < 2; ct++){
    int c  = m.colbase + ct*16 + m.lr;
    int mb = m.rowbase + m.lg*4;
    #pragma unroll
    for (int r = 0; r < 4; r++) R[(mb+r)*72 + c] = f2b(acc[ct][r] * scale);
  }
}
__device__ inline void storeT64(unsigned short* T, const f32x4 (&acc)[2], const MM& m, float scale){
  #pragma unroll
  for (int ct = 0; ct < 2; ct++){
    int c  = m.colbase + ct*16 + m.lr;
    int mb = m.rowbase + m.lg*4;
    short4v p;
    #pragma unroll
    for (int r = 0; r < 4; r++) p[r] = (short)f2b(acc[ct][r] * scale);
    *(short4v*)&T[c*72 + mb] = p;
  }
}
__device__ inline void storeSC(float* S, const f32x4 (&acc)[2], const MM& m, float scale){
  #pragma unroll
  for (int ct = 0; ct < 2; ct++){
    int c  = m.colbase + ct*16 + m.lr;
    int mb = m.rowbase + m.lg*4;
    #pragma unroll
    for (int r = 0; r < 4; r++) S[(mb+r)*66 + c] = acc[ct][r] * scale;
  }
}
// store C^T as bf16 to global (g holds dW^T [out][in]); 8B/lane contiguous
__device__ inline void storeGTb64(unsigned short* __restrict__ G, const f32x4 (&acc)[2],
                                  const MM& m, float scale){
  #pragma unroll
  for (int ct = 0; ct < 2; ct++){
    int c  = m.colbase + ct*16 + m.lr;   // out index
    int mb = m.rowbase + m.lg*4;         // in index base
    short4v p;
    #pragma unroll
    for (int r = 0; r < 4; r++) p[r] = (short)f2b(acc[ct][r] * scale);
    *(short4v*)&G[c*64 + mb] = p;
  }
}

// bf16 global 64x64 -> row LDS; 512 threads (one short8 each)
__device__ inline void loadTileBrow(unsigned short* R, const unsigned short* __restrict__ src,
                                    int stride, int tid){
  int i = tid >> 3, j8 = (tid & 7) * 8;
  *(short8*)&R[i*72 + j8] = *(const short8*)&src[(size_t)i*stride + j8];
}
// bf16 global 64x64 -> row + transposed LDS; 512 threads
__device__ inline void loadTileBrowT(unsigned short* R, unsigned short* T,
                                     const unsigned short* __restrict__ src,
                                     int stride, int tid){
  int i = tid >> 3, j8 = (tid & 7) * 8;
  short8 v = *(const short8*)&src[(size_t)i*stride + j8];
  *(short8*)&R[i*72 + j8] = v;
  #pragma unroll
  for (int jj = 0; jj < 8; jj++) T[(j8+jj)*72 + i] = (unsigned short)v[jj];
}

// =====================================================================
// K-FRONT: blocks [0, ROWS/4)   : wave-per-row rmsnorm (s hi, rq hi with
//                                 pad-zeroing, lr)
//          blocks [ROWS/4, +260): weight prep (transpose/convert bf16)
// =====================================================================
__global__ __launch_bounds__(256) void k_front(
    const float* __restrict__ seq, const float* __restrict__ wsn,
    const float* __restrict__ wrn, const float* __restrict__ wstep,
    const float* __restrict__ w_kv, const float* __restrict__ w_q,
    const float* __restrict__ wcomb,
    const float* __restrict__ wq, const float* __restrict__ wk,
    const float* __restrict__ wv1, const float* __restrict__ wv2,
    unsigned short* __restrict__ s_hi,
    unsigned short* __restrict__ rq_hi, float* __restrict__ lrp,
    unsigned short* __restrict__ wkvT_hi,
    unsigned short* __restrict__ wqT_hi, unsigned short* __restrict__ wcombT_hi,
    unsigned short* __restrict__ wpre)
{
  __shared__ float t[64][65];
  int tid = threadIdx.x;
  if (blockIdx.x >= ROWS/4){
    int blk = blockIdx.x - ROWS/4;
    if (blk < 256){
      const float* src; unsigned short *dhi;
      int R, C, bx, by;
      if (blk < 128){ src = w_kv;  dhi = wkvT_hi;  R = DIM; C = 2*DI; bx = blk & 15; by = blk >> 4; }
      else if (blk < 192){ int q = blk - 128; src = w_q;   dhi = wqT_hi;    R = DIM; C = DI;  bx = q & 7; by = q >> 3; }
      else               { int q = blk - 192; src = wcomb; dhi = wcombT_hi; R = DI;  C = DIM; bx = q & 7; by = q >> 3; }
      int c0 = bx * 64, r0 = by * 64;
      #pragma unroll
      for (int it = 0; it < 16; it++){
        int idx = it*256 + tid;
        int i = idx >> 6, j = idx & 63;
        t[i][j] = src[(size_t)(r0+i)*C + c0 + j];
      }
      __syncthreads();
      #pragma unroll
      for (int it = 0; it < 16; it++){
        int idx = it*256 + tid;
        int i = idx >> 6, j = idx & 63;
        dhi[(size_t)(c0+i)*R + r0 + j] = f2b(t[j][i]);
      }
    } else {
      int b = blk - 256;
      const float* src = (b==0) ? wq : (b==1) ? wk : (b==2) ? wv1 : wv2;
      #pragma unroll
      for (int it = 0; it < 16; it++){
        int idx = it*256 + tid;
        int i = idx >> 6, j = idx & 63;
        t[i][j] = src[i*64 + j];
      }
      __syncthreads();
      #pragma unroll
      for (int it = 0; it < 16; it++){
        int idx = it*256 + tid;
        int i = idx >> 6, j = idx & 63;
        wpre[b*4096 + i*64 + j] = f2b(t[j][i]);
        if (b == 3) wpre[4*4096 + i*64 + j] = f2b(t[i][j]);
      }
    }
    return;
  }
  // ---- rmsnorm part ----
  int wid = tid >> 6, lane = tid & 63;
  int row = blockIdx.x * 4 + wid;
  int b = row >> 12, tt = row & 4095;
  const float* x = seq + (size_t)row * DIM;
  float4 v0 = *(const float4*)&x[lane*4];
  float4 v1 = *(const float4*)&x[256 + lane*4];
  float xv[8] = {v0.x, v0.y, v0.z, v0.w, v1.x, v1.y, v1.z, v1.w};
  float ss = 0.f;
  #pragma unroll
  for (int j = 0; j < 8; j++) ss += xv[j]*xv[j];
  #pragma unroll
  for (int m = 1; m < 64; m <<= 1) ss += __shfl_xor(ss, m);
  float rinv = rsqrtf(ss * (1.f/DIM) + 1e-6f);

  float4 w0 = *(const float4*)&wsn[lane*4];
  float4 w1 = *(const float4*)&wsn[256 + lane*4];
  float wv[8] = {w0.x, w0.y, w0.z, w0.w, w1.x, w1.y, w1.z, w1.w};
  float sv[8];
  short4v h0, h1;
  #pragma unroll
  for (int j = 0; j < 8; j++){
    sv[j] = xv[j] * rinv * wv[j];
    unsigned short hi = f2b(sv[j]);
    if (j < 4) h0[j] = (short)hi; else h1[j-4] = (short)hi;
  }
  size_t sbase = (size_t)row*DIM + lane*4;
  *(short4v*)&s_hi[sbase] = h0; *(short4v*)&s_hi[sbase + 256] = h1;

  if (tt >= CH){
    float4 r0 = *(const float4*)&wrn[lane*4];
    float4 r1 = *(const float4*)&wrn[256 + lane*4];
    float rv[8] = {r0.x, r0.y, r0.z, r0.w, r1.x, r1.y, r1.z, r1.w};
    short4v rh0, rh1;
    #pragma unroll
    for (int j = 0; j < 8; j++){
      float q = xv[j] * rinv * rv[j];
      unsigned short hi = f2b(q);
      if (j < 4) rh0[j] = (short)hi; else rh1[j-4] = (short)hi;
    }
    size_t rbase = ((size_t)b*SEQ + (tt - CH))*DIM + lane*4;
    *(short4v*)&rq_hi[rbase] = rh0; *(short4v*)&rq_hi[rbase + 256] = rh1;
  } else {
    short4v z; z[0]=0; z[1]=0; z[2]=0; z[3]=0;
    size_t rbase = ((size_t)b*SEQ + (SEQ - CH + tt))*DIM + lane*4;
    *(short4v*)&rq_hi[rbase] = z; *(short4v*)&rq_hi[rbase + 256] = z;
  }

  float acc[8] = {0.f,0.f,0.f,0.f,0.f,0.f,0.f,0.f};
  #pragma unroll
  for (int j = 0; j < 8; j++){
    int e = (j < 4) ? (lane*4 + j) : (256 + lane*4 + (j-4));
    float4 wa = *(const float4*)&wstep[e*8];
    float4 wb = *(const float4*)&wstep[e*8 + 4];
    acc[0] += sv[j]*wa.x; acc[1] += sv[j]*wa.y; acc[2] += sv[j]*wa.z; acc[3] += sv[j]*wa.w;
    acc[4] += sv[j]*wb.x; acc[5] += sv[j]*wb.y; acc[6] += sv[j]*wb.z; acc[7] += sv[j]*wb.w;
  }
  #pragma unroll
  for (int m = 1; m < 64; m <<= 1){
    #pragma unroll
    for (int h = 0; h < 8; h++) acc[h] += __shfl_xor(acc[h], m);
  }
  float a = acc[0];
  #pragma unroll
  for (int h = 1; h < 8; h++) a = (lane == h) ? acc[h] : a;
  if (lane < 8)
    lrp[(size_t)row*HEADS + lane] = __expf(-15.f * sigmoidf_(a));
}

// =====================================================================
// K-MID (1-D, 896 blocks, 36.8KB LDS -> 4 blk/CU):
//  [0,512)  : kv GEMM  s_hi[8192][512] @ wkvT_hi[1024][512]^T -> kvb bf16
//  [512,768): q  GEMM  rq_hi @ wqT_hi -> qb bf16
//  [768,896): chunk stats
// =====================================================================
__global__ __launch_bounds__(256, 4) void k_mid(
    const unsigned short* __restrict__ s_hi, const unsigned short* __restrict__ rq_hi,
    const unsigned short* __restrict__ wkvT_hi, const unsigned short* __restrict__ wqT_hi,
    unsigned short* __restrict__ kvb, unsigned short* __restrict__ qb,
    const float* __restrict__ lrp, const float* __restrict__ wmom,
    const float* __restrict__ wdec,
    float* __restrict__ mg, float* __restrict__ dec, float* __restrict__ lrc)
{
  __shared__ __align__(16) unsigned short AhS[128*72];
  __shared__ __align__(16) unsigned short BhS[128*72];
  int tid = threadIdx.x;
  int blk = blockIdx.x;
  if (blk >= 768){
    int bid = blk - 768;
    float* smean = (float*)AhS;   // 2KB overlay
    int b = bid >> 6, ch = bid & 63;
    size_t off = ((size_t)(b*SEQ + ch*CH)) * DIM;
    for (int e = tid; e < DIM; e += 256){
      float acc = 0.f;
      for (int i = 0; i < CH; i++)
        acc += b2f(s_hi[off + (size_t)i*DIM + e]);
      smean[e] = acc * (1.f/CH);
    }
    __syncthreads();
    int gh = tid >> 5, l = tid & 31;
    float am = 0.f, ad = 0.f;
    for (int e = l; e < DIM; e += 32){
      float v = smean[e];
      am += v * wmom[e*HEADS + gh];
      ad += v * wdec[e*HEADS + gh];
    }
    const float* lrbase = lrp + ((size_t)(b*SEQ + ch*CH)) * HEADS + gh;
    float al = lrbase[(size_t)l*HEADS] + lrbase[(size_t)(l+32)*HEADS];
    #pragma unroll
    for (int m = 1; m < 32; m <<= 1){
      am += __shfl_xor(am, m);
      ad += __shfl_xor(ad, m);
      al += __shfl_xor(al, m);
    }
    if (l == 0){
      int o = (b*HEADS + gh)*NC + ch;
      mg[o]  = sigmoidf_(am);
      dec[o] = sigmoidf_(ad);
      lrc[o] = al * (1.f/CH);
    }
    return;
  }
  const unsigned short *Ahg, *Bhg; unsigned short* Cb;
  int N, nwg, bid;
  if (blk < 512){ Ahg = s_hi;  Bhg = wkvT_hi; Cb = kvb; N = 2*DI; nwg = 512; bid = blk; }
  else          { Ahg = rq_hi; Bhg = wqT_hi;  Cb = qb;  N = DI;   nwg = 256; bid = blk - 512; }
  const int K = DIM;
  int ntil = N >> 7;
  int swz = (bid & 7) * (nwg >> 3) + (bid >> 3);
  int m0 = (swz / ntil) * 128;
  int n0 = (swz % ntil) * 128;
  int wid = tid >> 6, lane = tid & 63;
  int lr = lane & 15, lg = lane >> 4;
  int wr = (wid >> 1) * 64, wc = (wid & 1) * 64;
  f32x4 acc[4][4];
  #pragma unroll
  for (int r = 0; r < 4; r++)
    #pragma unroll
    for (int c = 0; c < 4; c++) acc[r][c] = (f32x4){0.f,0.f,0.f,0.f};

  for (int k0 = 0; k0 < K; k0 += 64){
    #pragma unroll
    for (int it = 0; it < 4; it++){
      int idx = it*256 + tid;
      int row = idx >> 3, col8 = (idx & 7) * 8;
      *(short8*)&AhS[row*72 + col8] = *(const short8*)&Ahg[(size_t)(m0+row)*K + k0 + col8];
      *(short8*)&BhS[row*72 + col8] = *(const short8*)&Bhg[(size_t)(n0+row)*K + k0 + col8];
    }
    __syncthreads();
    #pragma unroll
    for (int ks = 0; ks < 2; ks++){
      short8 ah[4], bh[4];
      #pragma unroll
      for (int i = 0; i < 4; i++){
        ah[i] = *(const short8*)&AhS[(wr + i*16 + lr)*72 + ks*32 + lg*8];
        bh[i] = *(const short8*)&BhS[(wc + i*16 + lr)*72 + ks*32 + lg*8];
      }
      #pragma unroll
      for (int r = 0; r < 4; r++)
        #pragma unroll
        for (int c = 0; c < 4; c++)
          acc[r][c] = __builtin_amdgcn_mfma_f32_16x16x32_bf16(ah[r], bh[c], acc[r][c], 0, 0, 0);
    }
    __syncthreads();
  }
  #pragma unroll
  for (int rt = 0; rt < 4; rt++)
    #pragma unroll
    for (int ct = 0; ct < 4; ct++){
      int col = n0 + wc + ct*16 + lr;
      int rowb = m0 + wr + rt*16 + lg*4;
      #pragma unroll
      for (int r = 0; r < 4; r++)
        Cb[(size_t)(rowb+r)*N + col] = f2b(acc[rt][ct][r]);
    }
}

// =====================================================================
// K-GEMM (combine): C = A @ B^T 1-pass bf16 -> bf16, XCD-swizzled
// =====================================================================
__global__ __launch_bounds__(256, 4) void k_gemm1(
    const unsigned short* __restrict__ Ahg, const unsigned short* __restrict__ Bhg,
    unsigned short* __restrict__ Cb, int M, int N, int K)
{
  __shared__ __align__(16) unsigned short AhS[128*72];
  __shared__ __align__(16) unsigned short BhS[128*72];
  int tid = threadIdx.x;
  int nwg = gridDim.x * gridDim.y;
  int bid = blockIdx.y * gridDim.x + blockIdx.x;
  int swz = (bid & 7) * (nwg >> 3) + (bid >> 3);
  int m0 = (swz / gridDim.x) * 128;
  int n0 = (swz % gridDim.x) * 128;
  int wid = tid >> 6, lane = tid & 63;
  int lr = lane & 15, lg = lane >> 4;
  int wr = (wid >> 1) * 64, wc = (wid & 1) * 64;
  f32x4 acc[4][4];
  #pragma unroll
  for (int r = 0; r < 4; r++)
    #pragma unroll
    for (int c = 0; c < 4; c++) acc[r][c] = (f32x4){0.f,0.f,0.f,0.f};

  for (int k0 = 0; k0 < K; k0 += 64){
    #pragma unroll
    for (int it = 0; it < 4; it++){
      int idx = it*256 + tid;
      int row = idx >> 3, col8 = (idx & 7) * 8;
      *(short8*)&AhS[row*72 + col8] = *(const short8*)&Ahg[(size_t)(m0+row)*K + k0 + col8];
      *(short8*)&BhS[row*72 + col8] = *(const short8*)&Bhg[(size_t)(n0+row)*K + k0 + col8];
    }
    __syncthreads();
    #pragma unroll
    for (int ks = 0; ks < 2; ks++){
      short8 ah[4], bh[4];
      #pragma unroll
      for (int i = 0; i < 4; i++){
        ah[i] = *(const short8*)&AhS[(wr + i*16 + lr)*72 + ks*32 + lg*8];
        bh[i] = *(const short8*)&BhS[(wc + i*16 + lr)*72 + ks*32 + lg*8];
      }
      #pragma unroll
      for (int r = 0; r < 4; r++)
        #pragma unroll
        for (int c = 0; c < 4; c++)
          acc[r][c] = __builtin_amdgcn_mfma_f32_16x16x32_bf16(ah[r], bh[c], acc[r][c], 0, 0, 0);
    }
    __syncthreads();
  }
  #pragma unroll
  for (int rt = 0; rt < 4; rt++)
    #pragma unroll
    for (int ct = 0; ct < 4; ct++){
      int col = n0 + wc + ct*16 + lr;
      int rowb = m0 + wr + rt*16 + lg*4;
      #pragma unroll
      for (int r = 0; r < 4; r++)
        Cb[(size_t)(rowb+r)*N + col] = f2b(acc[rt][ct][r]);
    }
}

// =====================================================================
// K4: per-chunk attention fwd+bwd (8 waves, 512 thr, 127.5KB LDS)
// kvb [ROWS][2*DI] bf16: keys half = X, values half = target (bf16)
// =====================================================================
__global__ __launch_bounds__(512) void k_grads(
    const unsigned short* __restrict__ kvb,
    const unsigned short* __restrict__ wpre,
    const float* __restrict__ lrc, unsigned short* __restrict__ g)
{
  __shared__ __align__(16) unsigned short sm[12*TS];
  __shared__ __align__(16) float SC[64*66];
  unsigned short *Xr = sm,        *XT = sm + TS,
                 *s2 = sm + 2*TS, *s3 = sm + 3*TS, *s4 = sm + 4*TS,
                 *s5 = sm + 5*TS, *s6 = sm + 6*TS, *s7 = sm + 7*TS,
                 *s8 = sm + 8*TS, *s9 = sm + 9*TS, *s10 = sm + 10*TS,
                 *s11 = sm + 11*TS;
  unsigned short *SCu = (unsigned short*)SC;
  int chunk = blockIdx.x;
  int bh = chunk >> 6, t = chunk & 63;
  int b = bh >> 3, h = bh & 7;
  int tid = threadIdx.x;
  MM M = mmctx();
  const unsigned short* xb = kvb + ((size_t)(b*SEQ + t*CH)) * (2*DI) + h*DH;
  const unsigned short* tb = xb + DI;   // bf16 target
  float negLr = -lrc[bh*NC + t];
  f32x4 acc[2], accV[2];

  loadTileBrowT(Xr, XT, xb, 2*DI, tid);
  loadTileBrow(s2, wpre + 0*4096, 64, tid);   // WqT  [out][in]
  loadTileBrow(s3, wpre + 1*4096, 64, tid);   // WkT
  loadTileBrow(s4, wpre + 2*4096, 64, tid);   // Wv1T
  loadTileBrow(s5, wpre + 3*4096, 64, tid);   // Wv2T
  loadTileBrow(s6, wpre + 4*4096, 64, tid);   // Wv2 row [in][out]
  __syncthreads();
  mm64<false>(Xr, s2, acc, M);
  storeN64(s7, acc, M, 1.f); storeT64(s8, acc, M, 1.f);
  mm64<false>(Xr, s3, acc, M);
  storeN64(s9, acc, M, 1.f); storeT64(s10, acc, M, 1.f);
  mm64<false>(Xr, s4, accV, M);
  storeN64(s11, accV, M, 1.f);
  __syncthreads();
  storeT64(s2, accV, M, 1.f);
  mm64<false>(s7, s9, acc, M);
  storeSC(SC, acc, M, 0.125f);
  __syncthreads();
  {
    int row = tid >> 3, q = tid & 7;
    float p[8];
    float mx = -1e30f;
    #pragma unroll
    for (int cc = 0; cc < 8; cc++){
      int col = q*8 + cc;
      float x = SC[row*66 + col];
      p[cc] = (col <= row) ? x : -1e9f;
      mx = fmaxf(mx, p[cc]);
    }
    mx = fmaxf(mx, __shfl_xor(mx, 1));
    mx = fmaxf(mx, __shfl_xor(mx, 2));
    mx = fmaxf(mx, __shfl_xor(mx, 4));
    float sum = 0.f;
    #pragma unroll
    for (int cc = 0; cc < 8; cc++){ p[cc] = __expf(p[cc] - mx); sum += p[cc]; }
    sum += __shfl_xor(sum, 1);
    sum += __shfl_xor(sum, 2);
    sum += __shfl_xor(sum, 4);
    float inv = 1.f / sum;
    #pragma unroll
    for (int cc = 0; cc < 8; cc++){
      int col = q*8 + cc;
      unsigned short hh = f2b(p[cc] * inv);
      s7[row*72 + col] = hh;
      s9[col*72 + row] = hh;
    }
  }
  __syncthreads();
  mm64<false>(s7, s2, acc, M);
  storeN64(s3, acc, M, 1.f); storeT64(s4, acc, M, 1.f);
  __syncthreads();
  mm64<true>(s3, s5, acc, M);
  #pragma unroll
  for (int ct = 0; ct < 2; ct++){
    int c  = M.colbase + ct*16 + M.lr;
    int mb = M.rowbase + M.lg*4;
    #pragma unroll
    for (int r = 0; r < 4; r++){
      float t2 = (acc[ct][r] - b2f(tb[(size_t)(mb+r)*(2*DI) + c])) * (2.f/64.f);
      unsigned short hh = f2b(t2);
      Xr[(mb+r)*72 + c] = hh;
      s2[c*72 + (mb+r)] = hh;
    }
  }
  __syncthreads();
  mm64<true>(s4, s2, acc, M);
  storeGTb64(g + ((size_t)(3*NCHUNK + chunk))*4096, acc, M, negLr);
  mm64<false>(Xr, s6, acc, M);
  #pragma unroll
  for (int ct = 0; ct < 2; ct++){
    int c  = M.colbase + ct*16 + M.lr;
    int mb = M.rowbase + M.lg*4;
    #pragma unroll
    for (int r = 0; r < 4; r++){
      float x = b2f(s3[(mb+r)*72 + c]);
      float d = acc[ct][r] * dsilu_f(x);
      unsigned short hh = f2b(d);
      s5[(mb+r)*72 + c] = hh;
      SCu[c*72 + (mb+r)] = hh;
    }
  }
  __syncthreads();
  mm64<false>(s5, s11, acc, M);
  storeN64(Xr, acc, M, 1.f);
  mm64<false>(s9, SCu, acc, M);
  storeT64(s2, acc, M, 1.f);
  __syncthreads();
  {
    int row = tid >> 3, q = tid & 7;
    float da[8], a[8], rs = 0.f;
    #pragma unroll
    for (int cc = 0; cc < 8; cc++){
      int col = q*8 + cc;
      da[cc] = b2f(Xr[row*72 + col]);
      a[cc]  = b2f(s7[row*72 + col]);
      rs += da[cc]*a[cc];
    }
    rs += __shfl_xor(rs, 1);
    rs += __shfl_xor(rs, 2);
    rs += __shfl_xor(rs, 4);
    #pragma unroll
    for (int cc = 0; cc < 8; cc++){
      int col = q*8 + cc;
      unsigned short hh = f2b(a[cc] * (da[cc] - rs));
      s3[row*72 + col] = hh;
      s6[col*72 + row] = hh;
    }
  }
  mm64<false>(XT, s2, acc, M);
  storeGTb64(g + ((size_t)(2*NCHUNK + chunk))*4096, acc, M, negLr);
  __syncthreads();
  mm64<false>(s3, s10, acc, M);
  storeT64(Xr, acc, M, 0.125f);
  mm64<false>(s6, s8, acc, M);
  storeT64(s2, acc, M, 0.125f);
  __syncthreads();
  mm64<false>(XT, Xr, acc, M);
  storeGTb64(g + ((size_t)(0*NCHUNK + chunk))*4096, acc, M, negLr);
  mm64<false>(XT, s2, acc, M);
  storeGTb64(g + ((size_t)(1*NCHUNK + chunk))*4096, acc, M, negLr);
}

// =====================================================================
// K5: double associative scan over chunks; bf16 in/out (round-9 form)
// =====================================================================
__global__ __launch_bounds__(256) void k_scan(
    unsigned short* __restrict__ g, const float* __restrict__ mg, const float* __restrict__ dec,
    const float* __restrict__ wq, const float* __restrict__ wk,
    const float* __restrict__ wv1, const float* __restrict__ wv2)
{
  int idx = blockIdx.x * 256 + threadIdx.x;   // 0..131071
  int e = (idx & 2047) * 2;                   // even element index (out*64+in)
  int bh = (idx >> 11) & 15;
  int name = idx >> 15;
  const float* past = (name == 0) ? wq : (name == 1) ? wk : (name == 2) ? wv1 : wv2;
  float base0 = past[(e & 63)*64 + (e >> 6)];
  float base1 = past[((e+1) & 63)*64 + ((e+1) >> 6)];
  const float* mgb = mg + bh*NC;
  const float* dcb = dec + bh*NC;
  size_t baseoff = ((size_t)name*NCHUNK + (size_t)bh*NC)*4096 + e;
  float m0 = 0.f, u0 = 0.f, m1 = 0.f, u1 = 0.f;
  for (int t = 0; t < NC; t++){
    size_t off = baseoff + (size_t)t*4096;
    unsigned int v = *(const unsigned int*)&g[off];
    float su0 = b2f((unsigned short)(v & 0xffff));
    float su1 = b2f((unsigned short)(v >> 16));
    float gm = mgb[t], dc = dcb[t];
    m0 = gm*m0 + su0;  u0 = (1.f - dc)*u0 + m0;
    m1 = gm*m1 + su1;  u1 = (1.f - dc)*u1 + m1;
    unsigned int w = (unsigned int)f2b(base0 + u0) | ((unsigned int)f2b(base1 + u1) << 16);
    *(unsigned int*)&g[off] = w;
  }
}

// =====================================================================
// K6: retrieval attention; 8 waves, 72KB LDS (round-9 form); vals bf16 out
// =====================================================================
__global__ __launch_bounds__(512, 4) void k_retrieve(
    const unsigned short* __restrict__ qb, const unsigned short* __restrict__ Wg,
    unsigned short* __restrict__ vals_hi)
{
  __shared__ __align__(16) unsigned short sm[6*TS];
  __shared__ __align__(16) float SC[64*66];
  unsigned short *Xr = sm,       *Wt = sm + TS,   *Qr = sm + 2*TS,
                 *Kr = sm + 3*TS, *Vt = sm + 4*TS, *Hr = sm + 5*TS;
  unsigned short *Ar = (unsigned short*)SC;
  int chunk = blockIdx.x;
  int bh = chunk >> 6, t = chunk & 63;
  int b = bh >> 3, h = bh & 7;
  int tid = threadIdx.x;
  MM M = mmctx();
  const unsigned short* xb = qb + ((size_t)(b*SEQ + t*CH)) * DI + h*DH;
  f32x4 acc[2], accV[2];

  loadTileBrow(Xr, xb, DI, tid);
  loadTileBrow(Wt, Wg + ((size_t)(0*NCHUNK + chunk))*4096, 64, tid);
  __syncthreads();
  mm64<false>(Xr, Wt, acc, M); storeN64(Qr, acc, M, 1.f);
  loadTileBrow(Hr, Wg + ((size_t)(1*NCHUNK + chunk))*4096, 64, tid);
  __syncthreads();
  mm64<false>(Xr, Hr, acc, M); storeN64(Kr, acc, M, 1.f);
  loadTileBrow(Wt, Wg + ((size_t)(2*NCHUNK + chunk))*4096, 64, tid);
  __syncthreads();
  mm64<false>(Xr, Wt, accV, M); storeT64(Vt, accV, M, 1.f);
  mm64<false>(Qr, Kr, acc, M); storeSC(SC, acc, M, 0.125f);
  loadTileBrow(Hr, Wg + ((size_t)(3*NCHUNK + chunk))*4096, 64, tid);
  __syncthreads();
  {
    int row = tid >> 3, q = tid & 7;
    float p[8];
    float mx = -1e30f;
    #pragma unroll
    for (int cc = 0; cc < 8; cc++){
      int col = q*8 + cc;
      float x = SC[row*66 + col];
      p[cc] = (col <= row) ? x : -1e9f;
      mx = fmaxf(mx, p[cc]);
    }
    mx = fmaxf(mx, __shfl_xor(mx, 1));
    mx = fmaxf(mx, __shfl_xor(mx, 2));
    mx = fmaxf(mx, __shfl_xor(mx, 4));
    float sum = 0.f;
    #pragma unroll
    for (int cc = 0; cc < 8; cc++){ p[cc] = __expf(p[cc] - mx); sum += p[cc]; }
    sum += __shfl_xor(sum, 1);
    sum += __shfl_xor(sum, 2);
    sum += __shfl_xor(sum, 4);
    float inv = 1.f / sum;
    __syncthreads();   // drain SC reads before overlay write
    #pragma unroll
    for (int cc = 0; cc < 8; cc++){
      int col = q*8 + cc;
      Ar[row*72 + col] = f2b(p[cc] * inv);
    }
  }
  __syncthreads();
  mm64<false>(Ar, Vt, acc, M); storeN64(Kr, acc, M, 1.f);
  __syncthreads();
  mm64<true>(Kr, Hr, acc, M);
  #pragma unroll
  for (int ct = 0; ct < 2; ct++){
    int c  = M.colbase + ct*16 + M.lr;
    int mb = M.rowbase + M.lg*4;
    #pragma unroll
    for (int r = 0; r < 4; r++){
      size_t o = ((size_t)(b*SEQ + t*CH + mb + r))*DI + h*DH + c;
      vals_hi[o] = f2b(acc[ct][r]);
    }
  }
}

// =====================================================================
// K8: final rmsnorm + shift (wave-per-row, bf16 input); zeros rows r<CH
// =====================================================================
__global__ __launch_bounds__(256) void k_outnorm(
    const unsigned short* __restrict__ tmp, const float* __restrict__ wpn,
    float* __restrict__ out)
{
  int wid = threadIdx.x >> 6, lane = threadIdx.x & 63;
  int row = blockIdx.x * 4 + wid;           // 0..8191
  int b = row >> 12, r = row & 4095;
  float* dst = out + ((size_t)b*SEQ + r) * DIM;
  if (r < CH){
    float4 z = make_float4(0.f, 0.f, 0.f, 0.f);
    *(float4*)&dst[lane*8] = z;
    *(float4*)&dst[lane*8 + 4] = z;
    return;
  }
  const unsigned short* src = tmp + ((size_t)b*SEQ + (r - CH)) * DIM;
  short8 t0 = *(const short8*)&src[lane*8];
  float xv[8];
  #pragma unroll
  for (int j = 0; j < 8; j++) xv[j] = b2f((unsigned short)t0[j]);
  float ss = 0.f;
  #pragma unroll
  for (int j = 0; j < 8; j++) ss += xv[j]*xv[j];
  #pragma unroll
  for (int m = 1; m < 64; m <<= 1) ss += __shfl_xor(ss, m);
  float rinv = rsqrtf(ss * (1.f/DIM) + 1e-6f);
  float4 o0, o1;
  o0.x = xv[0]*rinv*wpn[lane*8+0]; o0.y = xv[1]*rinv*wpn[lane*8+1];
  o0.z = xv[2]*rinv*wpn[lane*8+2]; o0.w = xv[3]*rinv*wpn[lane*8+3];
  o1.x = xv[4]*rinv*wpn[lane*8+4]; o1.y = xv[5]*rinv*wpn[lane*8+5];
  o1.z = xv[6]*rinv*wpn[lane*8+6]; o1.w = xv[7]*rinv*wpn[lane*8+7];
  *(float4*)&dst[lane*8] = o0;
  *(float4*)&dst[lane*8 + 4] = o1;
}

// =====================================================================
extern "C" void kernel_launch(void* const* d_in, const int* in_sizes, int n_in,
                              void* d_out, int out_size, void* d_ws, size_t ws_size,
                              hipStream_t stream)
{
  (void)in_sizes; (void)n_in; (void)ws_size; (void)out_size;
  const float* seq   = (const float*)d_in[0];
  const float* wsn   = (const float*)d_in[1];
  const float* wrn   = (const float*)d_in[2];
  const float* wpn   = (const float*)d_in[3];
  const float* w_q   = (const float*)d_in[4];
  const float* w_kv  = (const float*)d_in[5];
  const float* wstep = (const float*)d_in[6];
  const float* wmom  = (const float*)d_in[7];
  const float* wdec  = (const float*)d_in[8];
  const float* wcomb = (const float*)d_in[9];
  const float* wq    = (const float*)d_in[10];
  const float* wk    = (const float*)d_in[11];
  const float* wv1   = (const float*)d_in[12];
  const float* wv2   = (const float*)d_in[13];
  float* out = (float*)d_out;

  char* p = (char*)d_ws;
  unsigned short* s_hi  = (unsigned short*)p; p += (size_t)ROWS*DIM*2;
  unsigned short* rq_hi = (unsigned short*)p; p += (size_t)ROWS*DIM*2;
  unsigned short* kvb   = (unsigned short*)p; p += (size_t)ROWS*2*DI*2;  // keys+target bf16
  unsigned short* qb    = (unsigned short*)p; p += (size_t)ROWS*DI*2;
  unsigned short* g     = (unsigned short*)p; p += (size_t)4*NCHUNK*4096*2;  // 32 MB
  float* lrp            = (float*)p;          p += (size_t)ROWS*HEADS*4;
  float* mg             = (float*)p;          p += (size_t)BH*NC*4;
  float* dec            = (float*)p;          p += (size_t)BH*NC*4;
  float* lrc            = (float*)p;          p += (size_t)BH*NC*4;
  unsigned short* wkvT_hi   = (unsigned short*)p; p += (size_t)(2*DI)*DIM*2;
  unsigned short* wqT_hi    = (unsigned short*)p; p += (size_t)DI*DIM*2;
  unsigned short* wcombT_hi = (unsigned short*)p; p += (size_t)DIM*DI*2;
  unsigned short* wpre      = (unsigned short*)p; p += (size_t)5*4096*2;
  unsigned short* vals_hi   = (unsigned short*)p; p += (size_t)ROWS*DI*2;
  // aliases over dead regions:
  unsigned short* tmp = s_hi;              // s_hi dead after k_mid

  // 1) rmsnorm + all weight prep (independent roots, one launch)
  k_front<<<ROWS/4 + 260, 256, 0, stream>>>(
      seq, wsn, wrn, wstep, w_kv, w_q, wcomb, wq, wk, wv1, wv2,
      s_hi, rq_hi, lrp, wkvT_hi, wqT_hi, wcombT_hi, wpre);
  // 2) kv GEMM (N=1024) + q GEMM + chunk stats, one 1-D launch, 4 blk/CU
  k_mid<<<896, 256, 0, stream>>>(
      s_hi, rq_hi, wkvT_hi, wqT_hi, kvb, qb,
      lrp, wmom, wdec, mg, dec, lrc);
  // 3) per-chunk grads
  k_grads<<<NCHUNK, 512, 0, stream>>>(kvb, wpre, lrc, g);
  // 4) scan
  k_scan<<<(4*BH*2048)/256, 256, 0, stream>>>(g, mg, dec, wq, wk, wv1, wv2);
  // 5) retrieval
  k_retrieve<<<NCHUNK, 512, 0, stream>>>(qb, g, vals_hi);
  // 6) combine GEMM (bf16 -> bf16 tmp)
  k_gemm1<<<dim3(DIM/128, ROWS/128), 256, 0, stream>>>(
      vals_hi, wcombT_hi, tmp, ROWS, DIM, DI);
  // 7) final norm + shift (includes zeroing of first CH rows)
  k_outnorm<<<ROWS/4, 256, 0, stream>>>(tmp, wpn, out);
}